// Round 5
// baseline (2083.580 us; speedup 1.0000x reference)
//
#include <hip/hip_runtime.h>

#define NROWS 8192
#define NCOLS 8192
#define DIM   512
#define BM   128              // rows per block
#define BN   256              // cols per ct tile
#define BK   16
#define NSPLIT 8
#define SLICE (NCOLS / NSPLIT)   // 1024
#define NCT   (SLICE / BN)       // 4
#define MR 8                  // rows per thread
#define NR 16                 // cols per thread
#define NCAND (NSPLIT * 2)    // 16 rescore candidates per row

// ---------------------------------------------------------------------------
// Kernel 1: f32 norms of d2 rows (selection only needs n2; phase-2 rescore
// recomputes exact distances from raw data, so no f64 norms needed).
// ---------------------------------------------------------------------------
__global__ __launch_bounds__(256) void dm_norms2(const float* __restrict__ d2,
                                                 float* __restrict__ n2) {
    const int wave = threadIdx.x >> 6;
    const int lane = threadIdx.x & 63;
    const int r = blockIdx.x * 4 + wave;
    const float* src = d2 + (size_t)r * DIM;
    float4 a = *(const float4*)(src + lane * 4);
    float4 b = *(const float4*)(src + 256 + lane * 4);
    float s = a.x * a.x + a.y * a.y + a.z * a.z + a.w * a.w
            + b.x * b.x + b.y * b.y + b.z * b.z + b.w * b.w;
#pragma unroll
    for (int m = 32; m >= 1; m >>= 1) s += __shfl_xor(s, m);
    if (lane == 0) n2[r] = s;
}

// ---------------------------------------------------------------------------
// Kernel 2: fused distance-GEMM + per-split top-2 selection (pure f32).
// Block: 128 rows x 1024-col slice, 256 threads, 8x16 register micro-tile.
// LDS: k-major As[16][128], Bs[16][256]; all LDS access <=2-way bank-aliased
// (free). 6 ds_read_b128 per 128 FMAs = 0.75 B/FMA (was 2.0) -> LDS pipe
// roughly balanced with VALU.
// Selection on s = n2[j] - 2*dot (monotone per row). f32 noise ~5e-5 vs
// 1st/2nd gap scale ~13: a true top-2 candidate drops out of a split's
// f32 top-2 only via TWO noise inversions (P ~ 1e-7 overall) -> the exact
// f64 rescore in kernel 3 makes the final output effectively exact.
// ---------------------------------------------------------------------------
__global__ __launch_bounds__(256, 2) void dm_match(const float* __restrict__ d1,
                                                   const float* __restrict__ d2,
                                                   const float* __restrict__ n2,
                                                   int* __restrict__ pi) {
    __shared__ float As[BK][BM];   // 8 KB
    __shared__ float Bs[BK][BN];   // 16 KB

    const int rb   = blockIdx.x >> 3;
    const int sp   = blockIdx.x & 7;
    const int row0 = rb * BM;
    const int colb = sp * SLICE;

    const int tid = threadIdx.x;
    const int tx  = tid & 15;          // col group 0..15 (16 cols each)
    const int ty  = tid >> 4;          // row group 0..15 (8 rows each)
    const int ar  = tid >> 1;          // A staging row 0..127
    const int ak  = (tid & 1) * 8;     // A staging k offset 0/8

    float v0[MR], v1[MR];
    int   i0[MR], i1[MR];
#pragma unroll
    for (int r = 0; r < MR; ++r) { v0[r] = 3.0e38f; v1[r] = 3.0e38f; i0[r] = 0; i1[r] = 0; }

    for (int ct = 0; ct < NCT; ++ct) {
        const int c0 = colb + ct * BN;
        float acc[MR][NR];
#pragma unroll
        for (int r = 0; r < MR; ++r)
#pragma unroll
            for (int c = 0; c < NR; ++c) acc[r][c] = 0.f;

        for (int kk = 0; kk < DIM; kk += BK) {
            // global loads issued before the barrier (overlap the wait)
            const float* ap = d1 + (size_t)(row0 + ar) * DIM + kk + ak;
            float4 a0 = *(const float4*)(ap);
            float4 a1 = *(const float4*)(ap + 4);
            const float* bp = d2 + (size_t)(c0 + tid) * DIM + kk;
            float4 b0 = *(const float4*)(bp);
            float4 b1 = *(const float4*)(bp + 4);
            float4 b2 = *(const float4*)(bp + 8);
            float4 b3 = *(const float4*)(bp + 12);
            __syncthreads();   // previous tile fully consumed
            As[ak + 0][ar] = a0.x; As[ak + 1][ar] = a0.y;
            As[ak + 2][ar] = a0.z; As[ak + 3][ar] = a0.w;
            As[ak + 4][ar] = a1.x; As[ak + 5][ar] = a1.y;
            As[ak + 6][ar] = a1.z; As[ak + 7][ar] = a1.w;
            Bs[ 0][tid] = b0.x; Bs[ 1][tid] = b0.y; Bs[ 2][tid] = b0.z; Bs[ 3][tid] = b0.w;
            Bs[ 4][tid] = b1.x; Bs[ 5][tid] = b1.y; Bs[ 6][tid] = b1.z; Bs[ 7][tid] = b1.w;
            Bs[ 8][tid] = b2.x; Bs[ 9][tid] = b2.y; Bs[10][tid] = b2.z; Bs[11][tid] = b2.w;
            Bs[12][tid] = b3.x; Bs[13][tid] = b3.y; Bs[14][tid] = b3.z; Bs[15][tid] = b3.w;
            __syncthreads();

#pragma unroll
            for (int k = 0; k < BK; ++k) {
                float a_[MR], b_[NR];
                *(float4*)&a_[0] = *(const float4*)&As[k][ty * 8];
                *(float4*)&a_[4] = *(const float4*)&As[k][ty * 8 + 4];
                *(float4*)&b_[ 0] = *(const float4*)&Bs[k][tx * 16];
                *(float4*)&b_[ 4] = *(const float4*)&Bs[k][tx * 16 + 4];
                *(float4*)&b_[ 8] = *(const float4*)&Bs[k][tx * 16 + 8];
                *(float4*)&b_[12] = *(const float4*)&Bs[k][tx * 16 + 12];
#pragma unroll
                for (int r = 0; r < MR; ++r)
#pragma unroll
                    for (int c = 0; c < NR; ++c)
                        acc[r][c] = fmaf(a_[r], b_[c], acc[r][c]);
            }
        }

        // top-2 update; columns ascend per thread -> strict < keeps the
        // lowest index first (top_k tie semantics).
        const int jb = c0 + tx * 16;
        float nn[NR];
        *(float4*)&nn[ 0] = *(const float4*)(n2 + jb);
        *(float4*)&nn[ 4] = *(const float4*)(n2 + jb + 4);
        *(float4*)&nn[ 8] = *(const float4*)(n2 + jb + 8);
        *(float4*)&nn[12] = *(const float4*)(n2 + jb + 12);
#pragma unroll
        for (int r = 0; r < MR; ++r) {
#pragma unroll
            for (int c = 0; c < NR; ++c) {
                const float s = fmaf(-2.f, acc[r][c], nn[c]);
                const int j = jb + c;
                if (s < v1[r]) {
                    if (s < v0[r]) { v1[r] = v0[r]; i1[r] = i0[r]; v0[r] = s; i0[r] = j; }
                    else           { v1[r] = s; i1[r] = j; }
                }
            }
        }
    }

    // merge top-2 across the 16 tx lanes of each row (lex compare on
    // (value, index) keeps lowest-index-first determinism).
#pragma unroll
    for (int r = 0; r < MR; ++r) {
        float a0 = v0[r], a1 = v1[r];
        int   ai0 = i0[r], ai1 = i1[r];
#pragma unroll
        for (int m = 1; m <= 8; m <<= 1) {
            float b0 = __shfl_xor(a0, m);
            float b1 = __shfl_xor(a1, m);
            int   bi0 = __shfl_xor(ai0, m);
            int   bi1 = __shfl_xor(ai1, m);
            if (b0 < a0 || (b0 == a0 && bi0 < ai0)) {
                if (a0 < b1 || (a0 == b1 && ai0 < bi1)) { a1 = a0; ai1 = ai0; }
                else                                    { a1 = b1; ai1 = bi1; }
                a0 = b0; ai0 = bi0;
            } else if (b0 < a1 || (b0 == a1 && bi0 < ai1)) {
                a1 = b0; ai1 = bi0;
            }
        }
        if (tx == 0) {
            const int row = row0 + ty * 8 + r;
            pi[(sp * NROWS + row) * 2 + 0] = ai0;
            pi[(sp * NROWS + row) * 2 + 1] = ai1;
        }
    }
}

// ---------------------------------------------------------------------------
// Kernel 3: exact f64 rescore of the 16 candidates per row, top-2, ratio
// test, outputs. One block per row; 16 threads per candidate.
// Output layout (floats): [0,8192) ratio-or-0, [8192,24576) idx pairs,
// [24576,32768) mask.
// ---------------------------------------------------------------------------
__global__ __launch_bounds__(256) void dm_rescore(const float* __restrict__ d1,
                                                  const float* __restrict__ d2,
                                                  const int* __restrict__ pi,
                                                  float* __restrict__ out) {
    __shared__ double cv[NCAND];
    __shared__ int    cj[NCAND];
    const int row  = blockIdx.x;
    const int cand = threadIdx.x >> 4;   // 0..15
    const int part = threadIdx.x & 15;   // 32 dims each
    const int sp   = cand >> 1;
    const int rk   = cand & 1;
    const int j = pi[(sp * NROWS + row) * 2 + rk];

    const float* a = d1 + (size_t)row * DIM + part * 32;
    const float* b = d2 + (size_t)j   * DIM + part * 32;
    double s = 0.0;
#pragma unroll
    for (int q = 0; q < 32; q += 4) {
        float4 x = *(const float4*)(a + q);
        float4 y = *(const float4*)(b + q);
        double e;
        e = (double)x.x - (double)y.x; s = fma(e, e, s);
        e = (double)x.y - (double)y.y; s = fma(e, e, s);
        e = (double)x.z - (double)y.z; s = fma(e, e, s);
        e = (double)x.w - (double)y.w; s = fma(e, e, s);
    }
    s += __shfl_xor(s, 1);
    s += __shfl_xor(s, 2);
    s += __shfl_xor(s, 4);
    s += __shfl_xor(s, 8);
    if (part == 0) { cv[cand] = s; cj[cand] = j; }
    __syncthreads();
    if (threadIdx.x == 0) {
        double b0 = 1.0e300, b1 = 1.0e300;
        int    j0 = 0, j1 = 0;
        for (int c = 0; c < NCAND; ++c) {
            const double v = cv[c];
            const int   jj = cj[c];
            if (v < b0 || (v == b0 && jj < j0)) { b1 = b0; j1 = j0; b0 = v; j0 = jj; }
            else if (v < b1 || (v == b1 && jj < j1)) { b1 = v; j1 = jj; }
        }
        const double d0  = sqrt(b0);
        const double d1v = sqrt(b1);
        const double dr  = d0 / d1v;
        const bool mask = (dr <= 0.8);
        out[row] = mask ? (float)dr : 0.f;
        out[NROWS + 2 * row]     = (float)row;
        out[NROWS + 2 * row + 1] = (float)j0;
        out[3 * NROWS + row] = mask ? 1.f : 0.f;
    }
}

extern "C" void kernel_launch(void* const* d_in, const int* in_sizes, int n_in,
                              void* d_out, int out_size, void* d_ws, size_t ws_size,
                              hipStream_t stream) {
    const float* d1 = (const float*)d_in[0];
    const float* d2 = (const float*)d_in[1];
    float* out = (float*)d_out;

    float* n2 = (float*)d_ws;                 // 8192 f32
    int*   pi = (int*)(n2 + NROWS);           // NSPLIT*8192*2 i32 (512 KB)

    dm_norms2<<<NROWS / 4, 256, 0, stream>>>(d2, n2);
    dm_match<<<(NROWS / BM) * NSPLIT, 256, 0, stream>>>(d1, d2, n2, pi);
    dm_rescore<<<NROWS, 256, 0, stream>>>(d1, d2, pi, out);
}

// Round 8
// 594.873 us; speedup vs baseline: 3.5026x; 3.5026x over previous
//
#include <hip/hip_runtime.h>

#define NROWS 8192
#define DIM   512

typedef __attribute__((ext_vector_type(8))) short short8;
typedef __attribute__((ext_vector_type(4))) float f32x4;

__device__ inline unsigned short f2bf(float x) {
    unsigned u = __float_as_uint(x);
    u += 0x7fffu + ((u >> 16) & 1u);
    return (unsigned short)(u >> 16);
}
__device__ inline float bf2f(unsigned short h) {
    return __uint_as_float(((unsigned)h) << 16);
}

// ---------------------------------------------------------------------------
// Fast path kernel 0: split f32 -> (hi, lo) bf16 arrays for d1 and d2.
// a.b ~= hi.hi + hi.lo + lo.hi  (lo.lo ~ 2^-18 dropped). 8 elems/thread.
// ---------------------------------------------------------------------------
__global__ __launch_bounds__(256) void dm_split(const float* __restrict__ d1,
                                                const float* __restrict__ d2,
                                                unsigned short* __restrict__ Ahi,
                                                unsigned short* __restrict__ Alo,
                                                unsigned short* __restrict__ Bhi,
                                                unsigned short* __restrict__ Blo) {
    const long long t = (long long)blockIdx.x * 256 + threadIdx.x;
    const long long e = t * 8;
    const long long half = (long long)NROWS * DIM;
    const bool second = (e >= half);
    const float* src = second ? d2 : d1;
    unsigned short* hid = second ? Bhi : Ahi;
    unsigned short* lod = second ? Blo : Alo;
    const long long o = second ? e - half : e;
    float4 x0 = *(const float4*)(src + o);
    float4 x1 = *(const float4*)(src + o + 4);
    float xs[8] = {x0.x, x0.y, x0.z, x0.w, x1.x, x1.y, x1.z, x1.w};
    unsigned short hs[8], ls[8];
#pragma unroll
    for (int i = 0; i < 8; ++i) {
        hs[i] = f2bf(xs[i]);
        ls[i] = f2bf(xs[i] - bf2f(hs[i]));
    }
    *(short8*)(hid + o) = *(short8*)hs;
    *(short8*)(lod + o) = *(short8*)ls;
}

// ---------------------------------------------------------------------------
// Fast path kernel 1: f32 norms of d2 rows.
// ---------------------------------------------------------------------------
__global__ __launch_bounds__(256) void dm_norms2(const float* __restrict__ d2,
                                                 float* __restrict__ n2) {
    const int wave = threadIdx.x >> 6;
    const int lane = threadIdx.x & 63;
    const int r = blockIdx.x * 4 + wave;
    const float* src = d2 + (size_t)r * DIM;
    float4 a = *(const float4*)(src + lane * 4);
    float4 b = *(const float4*)(src + 256 + lane * 4);
    float s = a.x * a.x + a.y * a.y + a.z * a.z + a.w * a.w
            + b.x * b.x + b.y * b.y + b.z * b.z + b.w * b.w;
#pragma unroll
    for (int m = 32; m >= 1; m >>= 1) s += __shfl_xor(s, m);
    if (lane == 0) n2[r] = s;
}

// ---------------------------------------------------------------------------
// Fast path kernel 2: bf16-split MFMA distance GEMM + fused per-split top-2.
// Virtual K = 1536 (48 K-tiles of 32): kt<16: Ahi.Bhi, kt<32: Ahi.Blo,
// else Alo.Bhi — all accumulated into the same f32 acc.
// Block: 256 thr = 4 waves; tile 128 rows x 128 cols; wave w owns rows
// [w*32, w*32+32) x all 128 cols -> 2 m-frags x 8 n-frags of 16x16x32.
// A fragments: global->reg direct (each wave loads exactly its own frags).
// B fragments: global->reg->LDS (frag-major, lane-linear 16B: conflict-free),
// shared by all 4 waves. One-K-tile register prefetch hides load latency.
// Epilogue: s = n2[c] - 2*dot, per-thread top-2 across cts, shfl-merge over
// the 16 col-lanes, write per-(row, split) {v0,v1,i0,i1} partials.
// ---------------------------------------------------------------------------
#define NSPLIT 16
#define SLICE (NROWS / NSPLIT)   // 512
#define NCT   (SLICE / 128)      // 4
#define NKT   48

__global__ __launch_bounds__(256, 2) void dm_match_mfma(
        const unsigned short* __restrict__ Ahi, const unsigned short* __restrict__ Alo,
        const unsigned short* __restrict__ Bhi, const unsigned short* __restrict__ Blo,
        const float* __restrict__ n2, float4* __restrict__ part) {
    __shared__ short8 Bs[8][64];   // 8 KB, frag-major

    const int tid = threadIdx.x;
    const int l   = tid & 63;
    const int w   = tid >> 6;
    const int rb  = blockIdx.x >> 4;
    const int sp  = blockIdx.x & (NSPLIT - 1);
    const int row0 = rb * 128;
    const int col0 = sp * SLICE;
    const int lr = l & 15;    // row/col within fragment
    const int lk = l >> 4;    // k-octet

    // A global element offsets (bf16 elems); constant across ct/kt except +k0
    const long long arow0 = (long long)(row0 + (2 * w + 0) * 16 + lr) * DIM + lk * 8;
    const long long arow1 = (long long)(row0 + (2 * w + 1) * 16 + lr) * DIM + lk * 8;

    float v0[8], v1[8];
    int   i0[8], i1[8];
#pragma unroll
    for (int s = 0; s < 8; ++s) { v0[s] = 3.0e38f; v1[s] = 3.0e38f; i0[s] = 0; i1[s] = 0; }

    for (int ct = 0; ct < NCT; ++ct) {
        const int colblk = col0 + ct * 128;
        const long long brow0 = (long long)(colblk + (2 * w + 0) * 16 + lr) * DIM + lk * 8;
        const long long brow1 = (long long)(colblk + (2 * w + 1) * 16 + lr) * DIM + lk * 8;

        f32x4 acc[2][8];
#pragma unroll
        for (int m = 0; m < 2; ++m)
#pragma unroll
            for (int n = 0; n < 8; ++n) acc[m][n] = (f32x4){0.f, 0.f, 0.f, 0.f};

        // prefetch kt = 0 (phase 0: Ahi, Bhi, k0 = 0)
        short8 ga0 = *(const short8*)(Ahi + arow0);
        short8 ga1 = *(const short8*)(Ahi + arow1);
        short8 gb0 = *(const short8*)(Bhi + brow0);
        short8 gb1 = *(const short8*)(Bhi + brow1);

        for (int kt = 0; kt < NKT; ++kt) {
            // prefetch kt+1 (clamped; last-iter loads are redundant but harmless)
            const int kn = (kt + 1 < NKT) ? kt + 1 : kt;
            const int pn = kn >> 4;
            const unsigned short* An = (pn < 2) ? Ahi : Alo;
            const unsigned short* Bn = (pn == 1) ? Blo : Bhi;
            const int k0n = (kn & 15) * 32;
            short8 na0 = *(const short8*)(An + arow0 + k0n);
            short8 na1 = *(const short8*)(An + arow1 + k0n);
            short8 nb0 = *(const short8*)(Bn + brow0 + k0n);
            short8 nb1 = *(const short8*)(Bn + brow1 + k0n);

            __syncthreads();                 // previous B tile fully consumed
            Bs[2 * w + 0][l] = gb0;          // lane-linear 16B: conflict-free
            Bs[2 * w + 1][l] = gb1;
            __syncthreads();

            short8 b0 = Bs[0][l], b1 = Bs[1][l], b2 = Bs[2][l], b3 = Bs[3][l];
            short8 b4 = Bs[4][l], b5 = Bs[5][l], b6 = Bs[6][l], b7 = Bs[7][l];

            acc[0][0] = __builtin_amdgcn_mfma_f32_16x16x32_bf16(ga0, b0, acc[0][0], 0, 0, 0);
            acc[0][1] = __builtin_amdgcn_mfma_f32_16x16x32_bf16(ga0, b1, acc[0][1], 0, 0, 0);
            acc[0][2] = __builtin_amdgcn_mfma_f32_16x16x32_bf16(ga0, b2, acc[0][2], 0, 0, 0);
            acc[0][3] = __builtin_amdgcn_mfma_f32_16x16x32_bf16(ga0, b3, acc[0][3], 0, 0, 0);
            acc[0][4] = __builtin_amdgcn_mfma_f32_16x16x32_bf16(ga0, b4, acc[0][4], 0, 0, 0);
            acc[0][5] = __builtin_amdgcn_mfma_f32_16x16x32_bf16(ga0, b5, acc[0][5], 0, 0, 0);
            acc[0][6] = __builtin_amdgcn_mfma_f32_16x16x32_bf16(ga0, b6, acc[0][6], 0, 0, 0);
            acc[0][7] = __builtin_amdgcn_mfma_f32_16x16x32_bf16(ga0, b7, acc[0][7], 0, 0, 0);
            acc[1][0] = __builtin_amdgcn_mfma_f32_16x16x32_bf16(ga1, b0, acc[1][0], 0, 0, 0);
            acc[1][1] = __builtin_amdgcn_mfma_f32_16x16x32_bf16(ga1, b1, acc[1][1], 0, 0, 0);
            acc[1][2] = __builtin_amdgcn_mfma_f32_16x16x32_bf16(ga1, b2, acc[1][2], 0, 0, 0);
            acc[1][3] = __builtin_amdgcn_mfma_f32_16x16x32_bf16(ga1, b3, acc[1][3], 0, 0, 0);
            acc[1][4] = __builtin_amdgcn_mfma_f32_16x16x32_bf16(ga1, b4, acc[1][4], 0, 0, 0);
            acc[1][5] = __builtin_amdgcn_mfma_f32_16x16x32_bf16(ga1, b5, acc[1][5], 0, 0, 0);
            acc[1][6] = __builtin_amdgcn_mfma_f32_16x16x32_bf16(ga1, b6, acc[1][6], 0, 0, 0);
            acc[1][7] = __builtin_amdgcn_mfma_f32_16x16x32_bf16(ga1, b7, acc[1][7], 0, 0, 0);

            ga0 = na0; ga1 = na1; gb0 = nb0; gb1 = nb1;
        }

        // fused selection on s = n2[c] - 2*dot (monotone per row).
        // C/D layout (m89): col = lane&15, row = (lane>>4)*4 + reg.
#pragma unroll
        for (int n = 0; n < 8; ++n) {
            const int c = colblk + n * 16 + lr;
            const float nv = n2[c];
#pragma unroll
            for (int m = 0; m < 2; ++m) {
#pragma unroll
                for (int r = 0; r < 4; ++r) {
                    const float s = fmaf(-2.f, acc[m][n][r], nv);
                    const int slot = m * 4 + r;
                    if (s < v1[slot]) {
                        if (s < v0[slot]) { v1[slot] = v0[slot]; i1[slot] = i0[slot];
                                            v0[slot] = s;        i0[slot] = c; }
                        else              { v1[slot] = s;        i1[slot] = c; }
                    }
                }
            }
        }
    }

    // merge top-2 across the 16 col-lanes of each row (lex (value, idx)).
#pragma unroll
    for (int slot = 0; slot < 8; ++slot) {
        float a0 = v0[slot], a1 = v1[slot];
        int   ai0 = i0[slot], ai1 = i1[slot];
#pragma unroll
        for (int m = 1; m <= 8; m <<= 1) {
            float b0 = __shfl_xor(a0, m);
            float b1 = __shfl_xor(a1, m);
            int   bi0 = __shfl_xor(ai0, m);
            int   bi1 = __shfl_xor(ai1, m);
            if (b0 < a0 || (b0 == a0 && bi0 < ai0)) {
                if (a0 < b1 || (a0 == b1 && ai0 < bi1)) { a1 = a0; ai1 = ai0; }
                else                                    { a1 = b1; ai1 = bi1; }
                a0 = b0; ai0 = bi0;
            } else if (b0 < a1 || (b0 == a1 && bi0 < ai1)) {
                a1 = b0; ai1 = bi0;
            }
        }
        if (lr == 0) {
            const int row = row0 + w * 32 + (slot >> 2) * 16 + lk * 4 + (slot & 3);
            float4 p;
            p.x = a0; p.y = a1;
            p.z = __int_as_float(ai0); p.w = __int_as_float(ai1);
            part[row * NSPLIT + sp] = p;
        }
    }
}

// ---------------------------------------------------------------------------
// Fast path kernel 3: exact f64 rescore of the 32 candidates/row, top-2,
// ratio test, outputs. Output (floats): [0,8192) ratio-or-0,
// [8192,24576) idx pairs, [24576,32768) mask.
// ---------------------------------------------------------------------------
#define NCAND 32
__global__ __launch_bounds__(256) void dm_rescore(const float* __restrict__ d1,
                                                  const float* __restrict__ d2,
                                                  const float4* __restrict__ part,
                                                  float* __restrict__ out) {
    __shared__ double cv[NCAND];
    __shared__ int    cj[NCAND];
    const int row = blockIdx.x;
    const int c = threadIdx.x >> 3;   // candidate 0..31
    const int p = threadIdx.x & 7;    // 64 dims each
    float4 P = part[row * NSPLIT + (c >> 1)];
    const int j = __float_as_int((c & 1) ? P.w : P.z);

    const float* a = d1 + (size_t)row * DIM + p * 64;
    const float* b = d2 + (size_t)j   * DIM + p * 64;
    double s = 0.0;
#pragma unroll
    for (int q = 0; q < 64; q += 4) {
        float4 x = *(const float4*)(a + q);
        float4 y = *(const float4*)(b + q);
        double e;
        e = (double)x.x - (double)y.x; s = fma(e, e, s);
        e = (double)x.y - (double)y.y; s = fma(e, e, s);
        e = (double)x.z - (double)y.z; s = fma(e, e, s);
        e = (double)x.w - (double)y.w; s = fma(e, e, s);
    }
    s += __shfl_xor(s, 1);
    s += __shfl_xor(s, 2);
    s += __shfl_xor(s, 4);
    if (p == 0) { cv[c] = s; cj[c] = j; }
    __syncthreads();
    if (threadIdx.x == 0) {
        double b0 = 1.0e300, b1 = 1.0e300;
        int    j0 = 0, j1 = 0;
        for (int q = 0; q < NCAND; ++q) {
            const double v = cv[q];
            const int   jj = cj[q];
            if (v < b0 || (v == b0 && jj < j0)) { b1 = b0; j1 = j0; b0 = v; j0 = jj; }
            else if (v < b1 || (v == b1 && jj < j1)) { b1 = v; j1 = jj; }
        }
        const double d0  = sqrt(b0);
        const double d1v = sqrt(b1);
        const double dr  = d0 / d1v;
        const bool mask = (dr <= 0.8);
        out[row] = mask ? (float)dr : 0.f;
        out[NROWS + 2 * row]     = (float)row;
        out[NROWS + 2 * row + 1] = (float)j0;
        out[3 * NROWS + row] = mask ? 1.f : 0.f;
    }
}

// ===========================================================================
// Fallback path (round-4 proven kernels) if ws_size is too small for the
// bf16-split arrays. f64-exact, ~2.1 ms, passes.
// ===========================================================================
__global__ __launch_bounds__(256) void dmfb_norms(const float* __restrict__ d1,
                                                  const float* __restrict__ d2,
                                                  double* __restrict__ n1,
                                                  double* __restrict__ n2) {
    const int wave = threadIdx.x >> 6;
    const int lane = threadIdx.x & 63;
    const int r = blockIdx.x * 4 + wave;
    const float* src = (r < NROWS) ? (d1 + (size_t)r * DIM)
                                   : (d2 + (size_t)(r - NROWS) * DIM);
    float4 a = *(const float4*)(src + lane * 4);
    float4 b = *(const float4*)(src + 256 + lane * 4);
    double s = (double)a.x * a.x + (double)a.y * a.y
             + (double)a.z * a.z + (double)a.w * a.w
             + (double)b.x * b.x + (double)b.y * b.y
             + (double)b.z * b.z + (double)b.w * b.w;
#pragma unroll
    for (int m = 32; m >= 1; m >>= 1) s += __shfl_xor(s, m);
    if (lane == 0) {
        if (r < NROWS) n1[r] = s;
        else           n2[r - NROWS] = s;
    }
}

__global__ __launch_bounds__(256) void dmfb_match(const float* __restrict__ d1,
                                                  const float* __restrict__ d2,
                                                  const double* __restrict__ n2,
                                                  double* __restrict__ pv0,
                                                  double* __restrict__ pv1,
                                                  int* __restrict__ pi0) {
    __shared__ float As[32][64];
    __shared__ float Bsh[32][64];
    const int rb   = blockIdx.x / 4;
    const int sp   = blockIdx.x % 4;
    const int row0 = rb * 64;
    const int col0 = sp * 2048;
    const int tid = threadIdx.x;
    const int tx  = tid & 15;
    const int ty  = tid >> 4;
    const int sc  = tid >> 3;
    const int sk  = (tid & 7) << 2;
    double v0[4], v1[4];
    int    i0[4];
#pragma unroll
    for (int r = 0; r < 4; ++r) { v0[r] = 1.0e300; v1[r] = 1.0e300; i0[r] = 0; }
    for (int ct = 0; ct < 32; ++ct) {
        const int c0 = col0 + ct * 64;
        double acc64[4][4];
#pragma unroll
        for (int r = 0; r < 4; ++r)
#pragma unroll
            for (int c = 0; c < 4; ++c) acc64[r][c] = 0.0;
        for (int kk = 0; kk < DIM; kk += 32) {
            float4 a0 = *(const float4*)(d1 + (size_t)(row0 + sc)      * DIM + kk + sk);
            float4 a1 = *(const float4*)(d1 + (size_t)(row0 + sc + 32) * DIM + kk + sk);
            float4 b0 = *(const float4*)(d2 + (size_t)(c0  + sc)      * DIM + kk + sk);
            float4 b1 = *(const float4*)(d2 + (size_t)(c0  + sc + 32) * DIM + kk + sk);
            __syncthreads();
            {
                const int wc0 = sc ^ sk;
                const int wc1 = (sc + 32) ^ sk;
                As[sk + 0][wc0] = a0.x; As[sk + 1][wc0] = a0.y;
                As[sk + 2][wc0] = a0.z; As[sk + 3][wc0] = a0.w;
                As[sk + 0][wc1] = a1.x; As[sk + 1][wc1] = a1.y;
                As[sk + 2][wc1] = a1.z; As[sk + 3][wc1] = a1.w;
                Bsh[sk + 0][wc0] = b0.x; Bsh[sk + 1][wc0] = b0.y;
                Bsh[sk + 2][wc0] = b0.z; Bsh[sk + 3][wc0] = b0.w;
                Bsh[sk + 0][wc1] = b1.x; Bsh[sk + 1][wc1] = b1.y;
                Bsh[sk + 2][wc1] = b1.z; Bsh[sk + 3][wc1] = b1.w;
            }
            __syncthreads();
            float acc[4][4];
#pragma unroll
            for (int r = 0; r < 4; ++r)
#pragma unroll
                for (int c = 0; c < 4; ++c) acc[r][c] = 0.f;
#pragma unroll
            for (int k = 0; k < 32; ++k) {
                const int rsw = (k >> 2) << 2;
                float4 a = *(const float4*)&As[k][(ty * 4) ^ rsw];
                float4 b = *(const float4*)&Bsh[k][(tx * 4) ^ rsw];
                acc[0][0] = fmaf(a.x, b.x, acc[0][0]);
                acc[0][1] = fmaf(a.x, b.y, acc[0][1]);
                acc[0][2] = fmaf(a.x, b.z, acc[0][2]);
                acc[0][3] = fmaf(a.x, b.w, acc[0][3]);
                acc[1][0] = fmaf(a.y, b.x, acc[1][0]);
                acc[1][1] = fmaf(a.y, b.y, acc[1][1]);
                acc[1][2] = fmaf(a.y, b.z, acc[1][2]);
                acc[1][3] = fmaf(a.y, b.w, acc[1][3]);
                acc[2][0] = fmaf(a.z, b.x, acc[2][0]);
                acc[2][1] = fmaf(a.z, b.y, acc[2][1]);
                acc[2][2] = fmaf(a.z, b.z, acc[2][2]);
                acc[2][3] = fmaf(a.z, b.w, acc[2][3]);
                acc[3][0] = fmaf(a.w, b.x, acc[3][0]);
                acc[3][1] = fmaf(a.w, b.y, acc[3][1]);
                acc[3][2] = fmaf(a.w, b.z, acc[3][2]);
                acc[3][3] = fmaf(a.w, b.w, acc[3][3]);
            }
#pragma unroll
            for (int r = 0; r < 4; ++r)
#pragma unroll
                for (int c = 0; c < 4; ++c) acc64[r][c] += (double)acc[r][c];
        }
        const int cbase = c0 + tx * 4;
        double nna[4];
#pragma unroll
        for (int c = 0; c < 4; ++c) nna[c] = n2[cbase + c];
#pragma unroll
        for (int r = 0; r < 4; ++r) {
#pragma unroll
            for (int c = 0; c < 4; ++c) {
                const double s = nna[c] - 2.0 * acc64[r][c];
                const int j = cbase + c;
                if (s < v0[r]) { v1[r] = v0[r]; v0[r] = s; i0[r] = j; }
                else if (s < v1[r]) { v1[r] = s; }
            }
        }
    }
#pragma unroll
    for (int r = 0; r < 4; ++r) {
        double a0 = v0[r], a1 = v1[r];
        int    ai = i0[r];
#pragma unroll
        for (int m = 1; m <= 8; m <<= 1) {
            double b0 = __shfl_xor(a0, m);
            double b1 = __shfl_xor(a1, m);
            int    bi = __shfl_xor(ai, m);
            bool take = (b0 < a0) || (b0 == a0 && bi < ai);
            if (take) { a1 = fmin(a0, b1); a0 = b0; ai = bi; }
            else      { a1 = fmin(a1, b0); }
        }
        if (tx == 0) {
            const int row = row0 + ty * 4 + r;
            pv0[sp * NROWS + row] = a0;
            pv1[sp * NROWS + row] = a1;
            pi0[sp * NROWS + row] = ai;
        }
    }
}

__global__ __launch_bounds__(256) void dmfb_finalize(const double* __restrict__ n1,
                                                     const double* __restrict__ pv0,
                                                     const double* __restrict__ pv1,
                                                     const int* __restrict__ pi0,
                                                     float* __restrict__ out) {
    const int i = blockIdx.x * blockDim.x + threadIdx.x;
    if (i >= NROWS) return;
    double a0 = pv0[i], a1 = pv1[i];
    int    ai = pi0[i];
#pragma unroll
    for (int h = 1; h < 4; ++h) {
        const double b0 = pv0[h * NROWS + i];
        const double b1 = pv1[h * NROWS + i];
        const int    bi = pi0[h * NROWS + i];
        bool take = (b0 < a0) || (b0 == a0 && bi < ai);
        if (take) { a1 = fmin(a0, b1); a0 = b0; ai = bi; }
        else      { a1 = fmin(a1, b0); }
    }
    const double nn = n1[i];
    const double d0  = sqrt(fmax(nn + a0, 0.0));
    const double d1v = sqrt(fmax(nn + a1, 0.0));
    const float ratio = (float)(d0 / d1v);
    const bool mask = (ratio <= 0.8f);
    out[i] = mask ? ratio : 0.f;
    out[NROWS + 2 * i]     = (float)i;
    out[NROWS + 2 * i + 1] = (float)ai;
    out[3 * NROWS + i] = mask ? 1.f : 0.f;
}

extern "C" void kernel_launch(void* const* d_in, const int* in_sizes, int n_in,
                              void* d_out, int out_size, void* d_ws, size_t ws_size,
                              hipStream_t stream) {
    const float* d1 = (const float*)d_in[0];
    const float* d2 = (const float*)d_in[1];
    float* out = (float*)d_out;

    const size_t ELEMS = (size_t)NROWS * DIM;              // 4,194,304
    const size_t need = 4 * ELEMS * 2 + NROWS * 4          // hi/lo arrays + n2
                      + (size_t)NROWS * NSPLIT * 16;       // partials
    if (ws_size >= need) {
        unsigned short* Ahi = (unsigned short*)d_ws;
        unsigned short* Alo = Ahi + ELEMS;
        unsigned short* Bhi = Alo + ELEMS;
        unsigned short* Blo = Bhi + ELEMS;
        float* n2 = (float*)(Blo + ELEMS);
        float4* part = (float4*)(n2 + NROWS);

        dm_split<<<(2 * ELEMS) / (256 * 8), 256, 0, stream>>>(d1, d2, Ahi, Alo, Bhi, Blo);
        dm_norms2<<<NROWS / 4, 256, 0, stream>>>(d2, n2);
        dm_match_mfma<<<(NROWS / 128) * NSPLIT, 256, 0, stream>>>(Ahi, Alo, Bhi, Blo, n2, part);
        dm_rescore<<<NROWS, 256, 0, stream>>>(d1, d2, part, out);
    } else {
        double* n1  = (double*)d_ws;
        double* n2  = n1 + NROWS;
        double* pv0 = n2 + NROWS;
        double* pv1 = pv0 + 4 * NROWS;
        int*    pi0 = (int*)(pv1 + 4 * NROWS);
        dmfb_norms<<<(2 * NROWS) / 4, 256, 0, stream>>>(d1, d2, n1, n2);
        dmfb_match<<<(NROWS / 64) * 4, 256, 0, stream>>>(d1, d2, n2, pv0, pv1, pi0);
        dmfb_finalize<<<NROWS / 256, 256, 0, stream>>>(n1, pv0, pv1, pi0, out);
    }
}